// Round 2
// baseline (219.039 us; speedup 1.0000x reference)
//
#include <hip/hip_runtime.h>
#include <hip/hip_bf16.h>
#include <stdint.h>

typedef __hip_bfloat16 bf16;
typedef __attribute__((ext_vector_type(8))) short short8;   // 8 x bf16 = 16B
typedef __attribute__((ext_vector_type(4))) float float4v;

#define MFMA16(a, b, c) __builtin_amdgcn_mfma_f32_16x16x32_bf16((a), (b), (c), 0, 0, 0)

static __device__ __forceinline__ short f2bf(float f) {
    bf16 h = __float2bfloat16(f);
    return *reinterpret_cast<short*>(&h);
}

// async global->LDS, 16B per lane; dest = lds_base (wave-uniform) + lane*16
static __device__ __forceinline__ void gl2lds16(const void* g, void* l) {
    __builtin_amdgcn_global_load_lds(
        (const __attribute__((address_space(1))) void*)g,
        (__attribute__((address_space(3))) void*)l, 16, 0, 0);
}

// =====================================================================
// Fused f32 -> bf16 convert (X, Wqkv(+zero pad to 3584 rows), Wout).
// =====================================================================
__global__ __launch_bounds__(256) void cvt_all(
    const float* __restrict__ a, bf16* __restrict__ A, int na,
    const float* __restrict__ b, bf16* __restrict__ B, int nbd, int nbt,
    const float* __restrict__ c, bf16* __restrict__ C, int nc)
{
    int i = (blockIdx.x * 256 + threadIdx.x) * 8;
    const float* src; bf16* dst;
    if (i < na) { src = a; dst = A; }
    else {
        i -= na;
        if (i < nbt) {
            if (i >= nbd) {              // zero-fill W pad rows (3456..3583)
                const short8 z = {0, 0, 0, 0, 0, 0, 0, 0};
                *(short8*)(B + i) = z;
                return;
            }
            src = b; dst = B;
        } else {
            i -= nbt;
            if (i >= nc) return;
            src = c; dst = C;
        }
    }
    const float4v x0 = *(const float4v*)(src + i);
    const float4v x1 = *(const float4v*)(src + i + 4);
    short8 v;
#pragma unroll
    for (int q = 0; q < 4; ++q) { v[q] = f2bf(x0[q]); v[q + 4] = f2bf(x1[q]); }
    *(short8*)(dst + i) = v;
}

// =====================================================================
// QKV GEMM, 8-phase counted-vmcnt schedule (T3+T4+T2+T5 port):
//   256x256 tile, BK=64, 512 thr = 8 waves (2M x 4N), per-wave 128x64.
//   LDS 128KB: A/B double-buffered, storage rows grouped by (mh|nh) so
//   each phase frees a contiguous 16KB half-tile for in-place restage.
//   Phase order (mh,nh): (0,0),(0,1),(1,1),(1,0).
//   Stage map: t.p0->A1(t+1), t.p1->B0(t+1), t.p2->A0(t+2), t.p3->B1(t+2);
//   one vmcnt(4) per K-tile (at p3, before its end barrier) covers all 4
//   halves of tile t+1 for every wave. Never vmcnt(0) except last-2 tail.
//   XOR swizzle: 16B chunk pos = chunk ^ (row&7)  (G4 recipe for 128B rows).
//   N padded 3456->3584 (zeroed); epilogue skips pad cols.
//   Scatter epilogue unchanged semantics: Q/K row-major repack, V transpose.
// =====================================================================
static __device__ __forceinline__ void phase_sync() {
    __builtin_amdgcn_s_barrier();
    asm volatile("s_waitcnt lgkmcnt(0)" ::: "memory");
    __builtin_amdgcn_sched_barrier(0);
    __builtin_amdgcn_s_setprio(1);
}
static __device__ __forceinline__ void phase_end() {
    __builtin_amdgcn_s_setprio(0);
    __builtin_amdgcn_s_barrier();
}

__global__ __launch_bounds__(512) void gemm_qkv(
    const bf16* __restrict__ X, const bf16* __restrict__ W,
    const float* __restrict__ bias,
    bf16* __restrict__ Qh, bf16* __restrict__ Kh, bf16* __restrict__ Vt)
{
    __shared__ __align__(16) bf16 SM[65536];   // 128 KB
    // A buf b: SM + b*16384  (256 storage rows x 64)
    // B buf b: SM + 32768 + b*16384
    // A storage row = mh*128 + wr*64 + (fm*16+l16); B: nh*128 + wc*32 + sub.

    const int tid  = threadIdx.x;
    const int wave = tid >> 6;
    const int lane = tid & 63;
    const int quad = lane >> 4;
    const int l16  = lane & 15;
    const int wr   = wave >> 2;      // 0..1  (M)
    const int wc   = wave & 3;       // 0..3  (N)
    const int m0 = blockIdx.x * 256;
    const int n0 = blockIdx.y * 256;
    const int cch = (lane & 7) ^ (lane >> 3);   // staging src chunk swizzle
    const int KT = 18;                          // 1152 / 64

    float4v acc[8][4];
    const float4v zf = {0.f, 0.f, 0.f, 0.f};
#pragma unroll
    for (int i = 0; i < 8; ++i)
#pragma unroll
        for (int j = 0; j < 4; ++j) acc[i][j] = zf;

    // stage one 128-storage-row half-tile (16KB): 8 waves x 2 issues x 8 rows
    auto stageA = [&](int buf, int kt, int h) {
#pragma unroll
        for (int i = 0; i < 2; ++i) {
            const int ls = (wave * 2 + i) * 8 + (lane >> 3);
            const int grow = m0 + ((ls >> 6) << 7) + (h << 6) + (ls & 63);
            gl2lds16(&X[(size_t)grow * 1152 + kt * 64 + cch * 8],
                     &SM[buf * 16384 + (h * 128 + (wave * 2 + i) * 8) * 64]);
        }
    };
    auto stageB = [&](int buf, int kt, int h) {
#pragma unroll
        for (int i = 0; i < 2; ++i) {
            const int ls = (wave * 2 + i) * 8 + (lane >> 3);
            const int grow = n0 + ((ls >> 5) << 6) + (h << 5) + (ls & 31);
            gl2lds16(&W[(size_t)grow * 1152 + kt * 64 + cch * 8],
                     &SM[32768 + buf * 16384 + (h * 128 + (wave * 2 + i) * 8) * 64]);
        }
    };

    auto ldA = [&](int buf, int mh, short8* a) {
#pragma unroll
        for (int fm = 0; fm < 4; ++fm)
#pragma unroll
            for (int ks = 0; ks < 2; ++ks) {
                const int sr = mh * 128 + wr * 64 + fm * 16 + l16;
                const int pos = (ks * 4 + quad) ^ (l16 & 7);
                a[fm * 2 + ks] = *(const short8*)&SM[buf * 16384 + sr * 64 + pos * 8];
            }
    };
    auto ldB = [&](int buf, int nh, short8* bv) {
#pragma unroll
        for (int fn = 0; fn < 2; ++fn)
#pragma unroll
            for (int ks = 0; ks < 2; ++ks) {
                const int sr = nh * 128 + wc * 32 + fn * 16 + l16;
                const int pos = (ks * 4 + quad) ^ (l16 & 7);
                bv[fn * 2 + ks] = *(const short8*)&SM[32768 + buf * 16384 + sr * 64 + pos * 8];
            }
    };
    auto mfma_q = [&](int mh, int nh, const short8* a, const short8* bv) {
#pragma unroll
        for (int fm = 0; fm < 4; ++fm)
#pragma unroll
            for (int fn = 0; fn < 2; ++fn)
#pragma unroll
                for (int ks = 0; ks < 2; ++ks)
                    acc[mh * 4 + fm][nh * 2 + fn] =
                        MFMA16(a[fm * 2 + ks], bv[fn * 2 + ks], acc[mh * 4 + fm][nh * 2 + fn]);
    };

    // prologue: A0(0),B1(0),A1(0),B0(0),A0(1),B1(1) then wait oldest 4 stages
    stageA(0, 0, 0); stageB(0, 0, 1);
    stageA(0, 0, 1); stageB(0, 0, 0);
    stageA(1, 1, 0); stageB(1, 1, 1);
    asm volatile("s_waitcnt vmcnt(4)" ::: "memory");
    __builtin_amdgcn_s_barrier();

#pragma unroll 1
    for (int t = 0; t < KT; ++t) {
        const int cbuf = t & 1, obuf = cbuf ^ 1;
        short8 a[8], bv[4];
        // p0: (0,0)
        ldA(cbuf, 0, a);
        ldB(cbuf, 0, bv);
        if (t + 1 < KT) stageA(obuf, t + 1, 1);
        phase_sync(); mfma_q(0, 0, a, bv); phase_end();
        // p1: (0,1)
        ldB(cbuf, 1, bv);
        if (t + 1 < KT) stageB(obuf, t + 1, 0);
        phase_sync(); mfma_q(0, 1, a, bv); phase_end();
        // p2: (1,1)  [A-half0 slot freed after p1 barrier -> restage in-place]
        ldA(cbuf, 1, a);
        if (t + 2 < KT) stageA(cbuf, t + 2, 0);
        phase_sync(); mfma_q(1, 1, a, bv); phase_end();
        // p3: (1,0)  [B-half1 slot freed after p2 barrier]
        ldB(cbuf, 0, bv);
        if (t + 2 < KT) stageB(cbuf, t + 2, 1);
        if (t + 2 < KT)      { asm volatile("s_waitcnt vmcnt(4)" ::: "memory"); }
        else if (t + 1 < KT) { asm volatile("s_waitcnt vmcnt(0)" ::: "memory"); }
        phase_sync(); mfma_q(1, 0, a, bv); phase_end();
    }

    // ---------------- epilogue: per-wave private scratter through LDS -----
    __syncthreads();
    const int colbase = n0 + wc * 64;
    if (colbase < 3456) {
        bf16* T = &SM[wave * 8192];          // 64 rows x 72 stride (per wave)
        const bool isV = (colbase >= 2304);
        float bcol[4];
#pragma unroll
        for (int cj = 0; cj < 4; ++cj) bcol[cj] = bias[colbase + cj * 16 + l16];

#pragma unroll 1
        for (int mh = 0; mh < 2; ++mh) {
            if (!isV) {
                // row-major [token][col]
#pragma unroll
                for (int cj = 0; cj < 4; ++cj)
#pragma unroll
                    for (int fm = 0; fm < 4; ++fm)
#pragma unroll
                        for (int r = 0; r < 4; ++r)
                            T[(fm * 16 + quad * 4 + r) * 72 + cj * 16 + l16] =
                                __float2bfloat16(acc[mh * 4 + fm][cj][r] + bcol[cj]);
            } else {
                // transposed [dim][token]
#pragma unroll
                for (int cj = 0; cj < 4; ++cj)
#pragma unroll
                    for (int fm = 0; fm < 4; ++fm)
#pragma unroll
                        for (int r = 0; r < 4; ++r)
                            T[(cj * 16 + l16) * 72 + fm * 16 + quad * 4 + r] =
                                __float2bfloat16(acc[mh * 4 + fm][cj][r] + bcol[cj]);
            }
            asm volatile("s_waitcnt lgkmcnt(0)" ::: "memory");
            const int rg0 = m0 + wr * 128 + mh * 64;
            if (!isV) {
                const bool isQ = colbase < 1152;
                const int cb2 = isQ ? colbase : colbase - 1152;
                bf16* outp = isQ ? Qh : Kh;
#pragma unroll
                for (int ch = 0; ch < 8; ++ch) {
                    const int colg = cb2 + ch * 8;
                    const int hh = colg / 72;
                    const int dd = colg - hh * 72;
                    *(short8*)(outp + ((size_t)hh * 4096 + rg0 + lane) * 72 + dd) =
                        *(const short8*)&T[lane * 72 + ch * 8];
                }
            } else {
                const int cd = colbase - 2304 + lane;
                const int hh = cd / 72;
                const int dm = cd - hh * 72;
                bf16* dst = &Vt[((size_t)hh * 72 + dm) * 4096 + rg0];
#pragma unroll
                for (int ch = 0; ch < 8; ++ch)
                    *(short8*)(dst + ch * 8) = *(const short8*)&T[lane * 72 + ch * 8];
            }
            asm volatile("s_waitcnt lgkmcnt(0)" ::: "memory");
        }
    }
}

// =====================================================================
// Out-proj GEMM: C[M][N] = X[M][K] @ W[N][K]^T + bias, f32 direct store.
// (unchanged, proven)
// =====================================================================
__global__ __launch_bounds__(256) void gemm_out(
    const bf16* __restrict__ X, const bf16* __restrict__ W,
    const float* __restrict__ bias, float* __restrict__ Cout,
    int M, int N, int K)
{
    __shared__ __align__(16) bf16 As[2][128 * 32];   // 16 KB
    __shared__ __align__(16) bf16 Bs[2][64 * 32];    //  8 KB

    const int tid  = threadIdx.x;
    const int wave = tid >> 6;
    const int lane = tid & 63;
    const int quad = lane >> 4;
    const int l16  = lane & 15;
    const int m0 = blockIdx.x * 128;
    const int n0 = blockIdx.y * 64;
    const int wm = (wave >> 1) * 64;
    const int wn = (wave & 1) * 32;

    const int lrow   = lane >> 2;
    const int lchunk = lane & 3;

    const int nIt = K >> 5;

    float4v acc[4][2];
    const float4v zf = {0.f, 0.f, 0.f, 0.f};
#pragma unroll
    for (int i = 0; i < 4; ++i)
#pragma unroll
        for (int j = 0; j < 2; ++j) acc[i][j] = zf;

    auto stage = [&](int buf, int k0) {
#pragma unroll
        for (int ii = 0; ii < 2; ++ii) {
            const int rbase = wave * 32 + ii * 16;
            const int r  = rbase + lrow;
            const int sc = lchunk ^ ((r >> 1) & 3);
            gl2lds16(&X[(size_t)(m0 + r) * K + k0 + sc * 8], &As[buf][rbase * 32]);
        }
        {
            const int rbase = wave * 16;
            const int r  = rbase + lrow;
            const int sc = lchunk ^ ((r >> 1) & 3);
            gl2lds16(&W[(size_t)(n0 + r) * K + k0 + sc * 8], &Bs[buf][rbase * 32]);
        }
    };

    stage(0, 0);

    for (int it = 0; it < nIt; ++it) {
        __syncthreads();
        if (it + 1 < nIt) stage((it + 1) & 1, (it + 1) * 32);

        const int b = it & 1;
        short8 af[4], bfr[2];
#pragma unroll
        for (int i = 0; i < 4; ++i) {
            const int r = wm + i * 16 + l16;
            af[i] = *(const short8*)&As[b][r * 32 + (quad ^ ((r >> 1) & 3)) * 8];
        }
#pragma unroll
        for (int j = 0; j < 2; ++j) {
            const int r = wn + j * 16 + l16;
            bfr[j] = *(const short8*)&Bs[b][r * 32 + (quad ^ ((r >> 1) & 3)) * 8];
        }
#pragma unroll
        for (int i = 0; i < 4; ++i)
#pragma unroll
            for (int j = 0; j < 2; ++j)
                acc[i][j] = MFMA16(af[i], bfr[j], acc[i][j]);
    }

    // epilogue: f32 direct stores (64B per quad, fully coalesced)
#pragma unroll
    for (int j = 0; j < 2; ++j) {
        const int col = n0 + wn + j * 16 + l16;
        const float bb = bias[col];
#pragma unroll
        for (int i = 0; i < 4; ++i) {
#pragma unroll
            for (int r = 0; r < 4; ++r) {
                const int row = m0 + wm + i * 16 + quad * 4 + r;
                Cout[(size_t)row * N + col] = acc[i][j][r] + bb;
            }
        }
    }
}

// =====================================================================
// Varlen flash attention (unchanged, proven)
// =====================================================================
__global__ __launch_bounds__(256) void attn_varlen(
    const bf16* __restrict__ Qh, const bf16* __restrict__ Kh,
    const bf16* __restrict__ Vt,
    const int* __restrict__ cu, bf16* __restrict__ AO)
{
    const float scale = 0.11785113019775793f;  // 72^-0.5
    __shared__ __align__(16) bf16 Ks[2][64 * 72];
    __shared__ __align__(16) bf16 Vs[2][80 * 64];
    __shared__ __align__(16) bf16 Ps[4][16 * 72];

    const int tid  = threadIdx.x;
    const int wave = tid >> 6;
    const int lane = tid & 63;
    const int quad = lane >> 4;
    const int l16  = lane & 15;
    const int h  = blockIdx.x & 15;
    const int qb = blockIdx.x >> 4;

    int seq_end = 0, q0 = -1, accb = 0, seq_start = 0;
    for (int i = 0; i < 8; ++i) {
        const int st = cu[i], en = cu[i + 1];
        const int nb = (en - st + 63) >> 6;
        if (q0 < 0 && qb < accb + nb) {
            seq_start = st; seq_end = en; q0 = st + (qb - accb) * 64;
        }
        accb += nb;
    }
    if (q0 < 0) return;

    // static V rows: dim 72 = ones (row-sum trick), 73..79 = zeros
    const bf16 onev  = __float2bfloat16(1.0f);
    const bf16 zerov = __float2bfloat16(0.0f);
    for (int t = tid; t < 1024; t += 256) {
        const int b = t >> 9, rr = (t >> 6) & 7, cc = t & 63;
        Vs[b][(72 + rr) * 64 + cc] = (rr == 0) ? onev : zerov;
    }

    const short8 z8 = {0, 0, 0, 0, 0, 0, 0, 0};

    int qrow_f = q0 + wave * 16 + l16; if (qrow_f > 4095) qrow_f = 4095;
    const bf16* qp = &Qh[((size_t)h * 4096 + qrow_f) * 72];
    short8 aq[3];
    aq[0] = *(const short8*)(qp + quad * 8);
    aq[1] = *(const short8*)(qp + 32 + quad * 8);
    aq[2] = (quad == 0) ? *(const short8*)(qp + 64) : z8;

    const bf16* kbase = &Kh[(size_t)h * 4096 * 72];
    auto stage = [&](int buf, int kv0) {
        const bf16* ksrc = kbase + (size_t)kv0 * 72;
        for (int i = wave; i < 9; i += 4)
            gl2lds16(ksrc + i * 512 + lane * 8, &Ks[buf][i * 512]);
        for (int i = wave; i < 9; i += 4) {
            const int d  = i * 8 + (lane >> 3);
            const int ch = (lane & 7) ^ (d & 7);
            gl2lds16(&Vt[((size_t)h * 72 + d) * 4096 + kv0 + ch * 8],
                     &Vs[buf][i * 512]);
        }
    };

    const float4v zf = {0.f, 0.f, 0.f, 0.f};
    float4v oacc[5];
#pragma unroll
    for (int d = 0; d < 5; ++d) oacc[d] = zf;

    const int kvbeg = seq_start & ~63;
    stage(0, kvbeg);

    for (int kv0 = kvbeg; kv0 < seq_end; kv0 += 64) {
        const int b = ((kv0 - kvbeg) >> 6) & 1;
        __syncthreads();
        if (kv0 + 64 < seq_end) stage(b ^ 1, kv0 + 64);

        float4v sc[4];
#pragma unroll
        for (int nt = 0; nt < 4; ++nt) {
            const bf16* kb = &Ks[b][(nt * 16 + l16) * 72];
            float4v s = zf;
            s = MFMA16(aq[0], *(const short8*)(kb + quad * 8), s);
            s = MFMA16(aq[1], *(const short8*)(kb + 32 + quad * 8), s);
            s = MFMA16(aq[2], (quad == 0) ? *(const short8*)(kb + 64) : z8, s);
            sc[nt] = s;
        }

#pragma unroll
        for (int nt = 0; nt < 4; ++nt) {
            const int kv = kv0 + nt * 16 + l16;
            const bool ok = (kv >= seq_start) && (kv < seq_end);
#pragma unroll
            for (int r = 0; r < 4; ++r) {
                const float p = ok ? __expf(sc[nt][r] * scale) : 0.f;
                Ps[wave][(quad * 4 + r) * 72 + nt * 16 + l16] = __float2bfloat16(p);
            }
        }

        const short8 ap0 = *(const short8*)&Ps[wave][l16 * 72 + quad * 8];
        const short8 ap1 = *(const short8*)&Ps[wave][l16 * 72 + 32 + quad * 8];

#pragma unroll
        for (int dt = 0; dt < 5; ++dt) {
            const int vr = dt * 16 + l16;
            const bf16* vb = &Vs[b][vr * 64];
            const short8 bv0 = *(const short8*)(vb + ((quad ^ (vr & 7)) * 8));
            const short8 bv1 = *(const short8*)(vb + (((quad + 4) ^ (vr & 7)) * 8));
            oacc[dt] = MFMA16(ap0, bv0, oacc[dt]);
            oacc[dt] = MFMA16(ap1, bv1, oacc[dt]);
        }
    }

#pragma unroll
    for (int r = 0; r < 4; ++r) {
        const int qrow = q0 + wave * 16 + quad * 4 + r;
        const float lv = __shfl(oacc[4][r], (lane & 48) | 8);
        if (qrow < seq_end) {
            const float inv = (lv > 0.f) ? (1.0f / lv) : 0.f;
#pragma unroll
            for (int d = 0; d < 5; ++d) {
                const int dim = d * 16 + l16;
                if (dim < 72)
                    AO[(size_t)qrow * 1152 + h * 72 + dim] =
                        __float2bfloat16(oacc[d][r] * inv);
            }
        }
    }
}

extern "C" void kernel_launch(void* const* d_in, const int* in_sizes, int n_in,
                              void* d_out, int out_size, void* d_ws, size_t ws_size,
                              hipStream_t stream)
{
    const float* Xf   = (const float*)d_in[0];
    const float* Wqkv = (const float*)d_in[1];
    const float* Bqkv = (const float*)d_in[2];
    const float* Wout = (const float*)d_in[3];
    const float* Bout = (const float*)d_in[4];
    const int*   cu   = (const int*)d_in[5];

    const size_t X16_B  = (size_t)4096 * 1152 * 2;
    const size_t WQ16_B = (size_t)3584 * 1152 * 2;   // padded to 3584 rows
    const size_t WO16_B = (size_t)1152 * 1152 * 2;
    const size_t H_B    = (size_t)16 * 4096 * 72 * 2;

    char* ws = (char*)d_ws;
    bf16* X16  = (bf16*)ws;
    bf16* WQ16 = (bf16*)(ws + X16_B);
    bf16* WO16 = (bf16*)(ws + X16_B + WQ16_B);
    bf16* Qh   = (bf16*)(ws + X16_B + WQ16_B + WO16_B);
    bf16* Kh   = (bf16*)(ws + X16_B + WQ16_B + WO16_B + H_B);
    bf16* Vt   = (bf16*)(ws + X16_B + WQ16_B + WO16_B + 2 * H_B);
    bf16* AO   = (bf16*)(ws + X16_B + WQ16_B + WO16_B + 3 * H_B);
    float* Out = (float*)d_out;

    dim3 blk(256);
    // f32->bf16 (+W pad zero-fill): (4096+3584+1152)*1152 / 8 / 256 = 4968
    cvt_all<<<dim3(4968), blk, 0, stream>>>(Xf, X16, 4096 * 1152,
                                            Wqkv, WQ16, 3456 * 1152, 3584 * 1152,
                                            Wout, WO16, 1152 * 1152);

    // QKV projection -> Qh/Kh (row-major repack) + Vt (transpose)
    gemm_qkv<<<dim3(16, 14), dim3(512), 0, stream>>>(X16, WQ16, Bqkv, Qh, Kh, Vt);
    // varlen attention (1-D grid, h = low 4 bits for XCD locality)
    attn_varlen<<<dim3(72 * 16), blk, 0, stream>>>(Qh, Kh, Vt, cu, AO);
    // output projection: 128x64 tiles, 576 blocks, direct f32 stores
    gemm_out<<<dim3(32, 18), blk, 0, stream>>>(AO, WO16, Bout, Out,
                                               4096, 1152, 1152);
}

// Round 3
// 199.353 us; speedup vs baseline: 1.0988x; 1.0988x over previous
//
#include <hip/hip_runtime.h>
#include <hip/hip_bf16.h>
#include <stdint.h>

typedef __hip_bfloat16 bf16;
typedef __attribute__((ext_vector_type(8))) short short8;   // 8 x bf16 = 16B
typedef __attribute__((ext_vector_type(4))) float float4v;

#define MFMA16(a, b, c) __builtin_amdgcn_mfma_f32_16x16x32_bf16((a), (b), (c), 0, 0, 0)

static __device__ __forceinline__ short f2bf(float f) {
    bf16 h = __float2bfloat16(f);
    return *reinterpret_cast<short*>(&h);
}

// async global->LDS, 16B per lane; dest = lds_base (wave-uniform) + lane*16
static __device__ __forceinline__ void gl2lds16(const void* g, void* l) {
    __builtin_amdgcn_global_load_lds(
        (const __attribute__((address_space(1))) void*)g,
        (__attribute__((address_space(3))) void*)l, 16, 0, 0);
}

// =====================================================================
// Fused f32 -> bf16 convert (X, Wqkv, Wout). One launch.  (R1-proven)
// =====================================================================
__global__ __launch_bounds__(256) void cvt_all(
    const float* __restrict__ a, bf16* __restrict__ A, int na,
    const float* __restrict__ b, bf16* __restrict__ B, int nb,
    const float* __restrict__ c, bf16* __restrict__ C, int nc)
{
    int i = (blockIdx.x * 256 + threadIdx.x) * 8;
    const float* src; bf16* dst;
    if (i < na)                 { src = a; dst = A; }
    else if (i < na + nb)       { i -= na; src = b; dst = B; }
    else                        { i -= na + nb; src = c; dst = C; if (i >= nc) return; }
    const float4v x0 = *(const float4v*)(src + i);
    const float4v x1 = *(const float4v*)(src + i + 4);
    short8 v;
#pragma unroll
    for (int q = 0; q < 4; ++q) { v[q] = f2bf(x0[q]); v[q + 4] = f2bf(x1[q]); }
    *(short8*)(dst + i) = v;
}

// =====================================================================
// QKV GEMM (R1 structure + counted-vmcnt triple-buffer pipeline):
//   128x128 tile, BK=32, 256 thr. LDS 48 KB = 3 bufs x (A 8KB + B 8KB).
//   Per iter: vmcnt(4) [tile it complete; tile it+1 stays IN FLIGHT across
//   the barrier — T4], raw s_barrier, stage tile it+2, ds_read + 16 MFMA.
//   Never vmcnt(0) except the last iteration. Race-safety: reads of buf b
//   (iter t) retire before that wave's barrier at iter t+1; restage of b
//   is issued after the barrier at iter t+3 — ordered for all waves.
//   Epilogue identical to R1 (proven clean WRITE_SIZE).
// =====================================================================
__global__ __launch_bounds__(256) void gemm_qkv(
    const bf16* __restrict__ X, const bf16* __restrict__ W,
    const float* __restrict__ bias,
    bf16* __restrict__ Qh, bf16* __restrict__ Kh, bf16* __restrict__ Vt,
    int M, int K)
{
    __shared__ __align__(16) bf16 SMEM[24576];   // 48 KB
    bf16* As = SMEM;            // [3][128*32]
    bf16* Bs = SMEM + 12288;    // [3][128*32]

    const int tid  = threadIdx.x;
    const int wave = tid >> 6;
    const int lane = tid & 63;
    const int quad = lane >> 4;
    const int l16  = lane & 15;
    const int m0 = blockIdx.x * 128;
    const int n0 = blockIdx.y * 128;
    const int wm = (wave >> 1) * 64;
    const int wn = (wave & 1) * 64;

    const int lrow   = lane >> 2;
    const int lchunk = lane & 3;

    const int nIt = K >> 5;

    float4v acc[4][4];
    const float4v zf = {0.f, 0.f, 0.f, 0.f};
#pragma unroll
    for (int i = 0; i < 4; ++i)
#pragma unroll
        for (int j = 0; j < 4; ++j) acc[i][j] = zf;

    auto stage = [&](int buf, int k0) {
#pragma unroll
        for (int ii = 0; ii < 2; ++ii) {
            const int rbase = wave * 32 + ii * 16;
            const int r  = rbase + lrow;
            const int sc = lchunk ^ ((r >> 1) & 3);
            gl2lds16(&X[(size_t)(m0 + r) * K + k0 + sc * 8], &As[buf * 4096 + rbase * 32]);
            gl2lds16(&W[(size_t)(n0 + r) * K + k0 + sc * 8], &Bs[buf * 4096 + rbase * 32]);
        }
    };

    // prologue: 2 tiles in flight (8 vmcnt ops/wave)
    stage(0, 0);
    stage(1, 32);

    int cb = 0;                       // compute buffer = it % 3
    for (int it = 0; it < nIt; ++it) {
        // wait tile 'it' only; tile it+1 (4 ops) remains in flight
        if (it + 1 < nIt) { asm volatile("s_waitcnt vmcnt(4)" ::: "memory"); }
        else              { asm volatile("s_waitcnt vmcnt(0)" ::: "memory"); }
        __builtin_amdgcn_s_barrier();
        asm volatile("" ::: "memory");          // compiler fence: no LDS-op motion

        if (it + 2 < nIt) {
            const int sb = (cb >= 1) ? cb - 1 : 2;   // (it+2) % 3
            stage(sb, (it + 2) * 32);
        }

        short8 af[4], bfr[4];
#pragma unroll
        for (int i = 0; i < 4; ++i) {
            const int r = wm + i * 16 + l16;
            af[i] = *(const short8*)&As[cb * 4096 + r * 32 + (quad ^ ((r >> 1) & 3)) * 8];
        }
#pragma unroll
        for (int j = 0; j < 4; ++j) {
            const int r = wn + j * 16 + l16;
            bfr[j] = *(const short8*)&Bs[cb * 4096 + r * 32 + (quad ^ ((r >> 1) & 3)) * 8];
        }
#pragma unroll
        for (int i = 0; i < 4; ++i)
#pragma unroll
            for (int j = 0; j < 4; ++j)
                acc[i][j] = MFMA16(af[i], bfr[j], acc[i][j]);

        cb = (cb == 2) ? 0 : cb + 1;
    }

    bf16* T = SMEM;   // epilogue scratch (all staging/DMA drained by last iter)

    if (n0 >= 2304) {
        // ---- V: transpose to Vt[h][d][tok], coalesced 16B stores ----
#pragma unroll 1
        for (int half = 0; half < 2; ++half) {
            __syncthreads();
            if ((wave & 1) == half) {
#pragma unroll
                for (int j = 0; j < 4; ++j) {
                    const int col = n0 + wn + j * 16 + l16;
                    const float bb = bias[col];
#pragma unroll
                    for (int i = 0; i < 4; ++i)
#pragma unroll
                        for (int r = 0; r < 4; ++r)
                            T[(j * 16 + l16) * 136 + wm + i * 16 + quad * 4 + r] =
                                __float2bfloat16(acc[i][j][r] + bb);
                }
            }
            __syncthreads();
            const int dd   = tid >> 2;
            const int tok0 = (tid & 3) * 32;
            const int colg = n0 + half * 64 + dd - 2304;
            const int hh   = colg / 72;
            const int dm   = colg - hh * 72;
            bf16* dst = &Vt[((size_t)hh * 72 + dm) * 4096 + m0 + tok0];
#pragma unroll
            for (int k = 0; k < 4; ++k)
                *(short8*)(dst + k * 8) = *(const short8*)&T[dd * 136 + tok0 + k * 8];
        }
        return;
    }

    // ---- Q/K: row-major repack through LDS, 16B stores ----
#pragma unroll 1
    for (int half = 0; half < 2; ++half) {
        __syncthreads();
        if ((wave >> 1) == half) {   // waves whose wm == half*64
#pragma unroll
            for (int j = 0; j < 4; ++j) {
                const int col = n0 + wn + j * 16 + l16;
                const float bb = bias[col];
#pragma unroll
                for (int i = 0; i < 4; ++i)
#pragma unroll
                    for (int r = 0; r < 4; ++r)
                        T[(i * 16 + quad * 4 + r) * 136 + wn + j * 16 + l16] =
                            __float2bfloat16(acc[i][j][r] + bb);
            }
        }
        __syncthreads();
        const int rloc = tid >> 2;
        const int row  = m0 + half * 64 + rloc;
        const int c0   = (tid & 3) * 32;
#pragma unroll
        for (int k = 0; k < 4; ++k) {
            const int colg = n0 + c0 + k * 8;
            const bool isQ = (colg < 1152);
            const int cc = isQ ? colg : colg - 1152;
            const int hh = cc / 72;
            const int dd = cc - hh * 72;
            bf16* dst = (isQ ? Qh : Kh) + ((size_t)hh * 4096 + row) * 72 + dd;
            *(short8*)dst = *(const short8*)&T[rloc * 136 + c0 + k * 8];
        }
    }
}

// =====================================================================
// Out-proj GEMM: C[M][N] = X[M][K] @ W[N][K]^T + bias, f32 direct store.
// (R1-proven, unchanged)
// =====================================================================
__global__ __launch_bounds__(256) void gemm_out(
    const bf16* __restrict__ X, const bf16* __restrict__ W,
    const float* __restrict__ bias, float* __restrict__ Cout,
    int M, int N, int K)
{
    __shared__ __align__(16) bf16 As[2][128 * 32];   // 16 KB
    __shared__ __align__(16) bf16 Bs[2][64 * 32];    //  8 KB

    const int tid  = threadIdx.x;
    const int wave = tid >> 6;
    const int lane = tid & 63;
    const int quad = lane >> 4;
    const int l16  = lane & 15;
    const int m0 = blockIdx.x * 128;
    const int n0 = blockIdx.y * 64;
    const int wm = (wave >> 1) * 64;
    const int wn = (wave & 1) * 32;

    const int lrow   = lane >> 2;
    const int lchunk = lane & 3;

    const int nIt = K >> 5;

    float4v acc[4][2];
    const float4v zf = {0.f, 0.f, 0.f, 0.f};
#pragma unroll
    for (int i = 0; i < 4; ++i)
#pragma unroll
        for (int j = 0; j < 2; ++j) acc[i][j] = zf;

    auto stage = [&](int buf, int k0) {
#pragma unroll
        for (int ii = 0; ii < 2; ++ii) {
            const int rbase = wave * 32 + ii * 16;
            const int r  = rbase + lrow;
            const int sc = lchunk ^ ((r >> 1) & 3);
            gl2lds16(&X[(size_t)(m0 + r) * K + k0 + sc * 8], &As[buf][rbase * 32]);
        }
        {
            const int rbase = wave * 16;
            const int r  = rbase + lrow;
            const int sc = lchunk ^ ((r >> 1) & 3);
            gl2lds16(&W[(size_t)(n0 + r) * K + k0 + sc * 8], &Bs[buf][rbase * 32]);
        }
    };

    stage(0, 0);

    for (int it = 0; it < nIt; ++it) {
        __syncthreads();
        if (it + 1 < nIt) stage((it + 1) & 1, (it + 1) * 32);

        const int b = it & 1;
        short8 af[4], bfr[2];
#pragma unroll
        for (int i = 0; i < 4; ++i) {
            const int r = wm + i * 16 + l16;
            af[i] = *(const short8*)&As[b][r * 32 + (quad ^ ((r >> 1) & 3)) * 8];
        }
#pragma unroll
        for (int j = 0; j < 2; ++j) {
            const int r = wn + j * 16 + l16;
            bfr[j] = *(const short8*)&Bs[b][r * 32 + (quad ^ ((r >> 1) & 3)) * 8];
        }
#pragma unroll
        for (int i = 0; i < 4; ++i)
#pragma unroll
            for (int j = 0; j < 2; ++j)
                acc[i][j] = MFMA16(af[i], bfr[j], acc[i][j]);
    }

    // epilogue: f32 direct stores (64B per quad, fully coalesced)
#pragma unroll
    for (int j = 0; j < 2; ++j) {
        const int col = n0 + wn + j * 16 + l16;
        const float bb = bias[col];
#pragma unroll
        for (int i = 0; i < 4; ++i) {
#pragma unroll
            for (int r = 0; r < 4; ++r) {
                const int row = m0 + wm + i * 16 + quad * 4 + r;
                Cout[(size_t)row * N + col] = acc[i][j][r] + bb;
            }
        }
    }
}

// =====================================================================
// Varlen flash attention (R1-proven, unchanged)
// =====================================================================
__global__ __launch_bounds__(256) void attn_varlen(
    const bf16* __restrict__ Qh, const bf16* __restrict__ Kh,
    const bf16* __restrict__ Vt,
    const int* __restrict__ cu, bf16* __restrict__ AO)
{
    const float scale = 0.11785113019775793f;  // 72^-0.5
    __shared__ __align__(16) bf16 Ks[2][64 * 72];
    __shared__ __align__(16) bf16 Vs[2][80 * 64];
    __shared__ __align__(16) bf16 Ps[4][16 * 72];

    const int tid  = threadIdx.x;
    const int wave = tid >> 6;
    const int lane = tid & 63;
    const int quad = lane >> 4;
    const int l16  = lane & 15;
    const int h  = blockIdx.x & 15;
    const int qb = blockIdx.x >> 4;

    int seq_end = 0, q0 = -1, accb = 0, seq_start = 0;
    for (int i = 0; i < 8; ++i) {
        const int st = cu[i], en = cu[i + 1];
        const int nb = (en - st + 63) >> 6;
        if (q0 < 0 && qb < accb + nb) {
            seq_start = st; seq_end = en; q0 = st + (qb - accb) * 64;
        }
        accb += nb;
    }
    if (q0 < 0) return;

    // static V rows: dim 72 = ones (row-sum trick), 73..79 = zeros
    const bf16 onev  = __float2bfloat16(1.0f);
    const bf16 zerov = __float2bfloat16(0.0f);
    for (int t = tid; t < 1024; t += 256) {
        const int b = t >> 9, rr = (t >> 6) & 7, cc = t & 63;
        Vs[b][(72 + rr) * 64 + cc] = (rr == 0) ? onev : zerov;
    }

    const short8 z8 = {0, 0, 0, 0, 0, 0, 0, 0};

    int qrow_f = q0 + wave * 16 + l16; if (qrow_f > 4095) qrow_f = 4095;
    const bf16* qp = &Qh[((size_t)h * 4096 + qrow_f) * 72];
    short8 aq[3];
    aq[0] = *(const short8*)(qp + quad * 8);
    aq[1] = *(const short8*)(qp + 32 + quad * 8);
    aq[2] = (quad == 0) ? *(const short8*)(qp + 64) : z8;

    const bf16* kbase = &Kh[(size_t)h * 4096 * 72];
    auto stage = [&](int buf, int kv0) {
        const bf16* ksrc = kbase + (size_t)kv0 * 72;
        for (int i = wave; i < 9; i += 4)
            gl2lds16(ksrc + i * 512 + lane * 8, &Ks[buf][i * 512]);
        for (int i = wave; i < 9; i += 4) {
            const int d  = i * 8 + (lane >> 3);
            const int ch = (lane & 7) ^ (d & 7);
            gl2lds16(&Vt[((size_t)h * 72 + d) * 4096 + kv0 + ch * 8],
                     &Vs[buf][i * 512]);
        }
    };

    const float4v zf = {0.f, 0.f, 0.f, 0.f};
    float4v oacc[5];
#pragma unroll
    for (int d = 0; d < 5; ++d) oacc[d] = zf;

    const int kvbeg = seq_start & ~63;
    stage(0, kvbeg);

    for (int kv0 = kvbeg; kv0 < seq_end; kv0 += 64) {
        const int b = ((kv0 - kvbeg) >> 6) & 1;
        __syncthreads();
        if (kv0 + 64 < seq_end) stage(b ^ 1, kv0 + 64);

        float4v sc[4];
#pragma unroll
        for (int nt = 0; nt < 4; ++nt) {
            const bf16* kb = &Ks[b][(nt * 16 + l16) * 72];
            float4v s = zf;
            s = MFMA16(aq[0], *(const short8*)(kb + quad * 8), s);
            s = MFMA16(aq[1], *(const short8*)(kb + 32 + quad * 8), s);
            s = MFMA16(aq[2], (quad == 0) ? *(const short8*)(kb + 64) : z8, s);
            sc[nt] = s;
        }

#pragma unroll
        for (int nt = 0; nt < 4; ++nt) {
            const int kv = kv0 + nt * 16 + l16;
            const bool ok = (kv >= seq_start) && (kv < seq_end);
#pragma unroll
            for (int r = 0; r < 4; ++r) {
                const float p = ok ? __expf(sc[nt][r] * scale) : 0.f;
                Ps[wave][(quad * 4 + r) * 72 + nt * 16 + l16] = __float2bfloat16(p);
            }
        }

        const short8 ap0 = *(const short8*)&Ps[wave][l16 * 72 + quad * 8];
        const short8 ap1 = *(const short8*)&Ps[wave][l16 * 72 + 32 + quad * 8];

#pragma unroll
        for (int dt = 0; dt < 5; ++dt) {
            const int vr = dt * 16 + l16;
            const bf16* vb = &Vs[b][vr * 64];
            const short8 bv0 = *(const short8*)(vb + ((quad ^ (vr & 7)) * 8));
            const short8 bv1 = *(const short8*)(vb + (((quad + 4) ^ (vr & 7)) * 8));
            oacc[dt] = MFMA16(ap0, bv0, oacc[dt]);
            oacc[dt] = MFMA16(ap1, bv1, oacc[dt]);
        }
    }

#pragma unroll
    for (int r = 0; r < 4; ++r) {
        const int qrow = q0 + wave * 16 + quad * 4 + r;
        const float lv = __shfl(oacc[4][r], (lane & 48) | 8);
        if (qrow < seq_end) {
            const float inv = (lv > 0.f) ? (1.0f / lv) : 0.f;
#pragma unroll
            for (int d = 0; d < 5; ++d) {
                const int dim = d * 16 + l16;
                if (dim < 72)
                    AO[(size_t)qrow * 1152 + h * 72 + dim] =
                        __float2bfloat16(oacc[d][r] * inv);
            }
        }
    }
}

extern "C" void kernel_launch(void* const* d_in, const int* in_sizes, int n_in,
                              void* d_out, int out_size, void* d_ws, size_t ws_size,
                              hipStream_t stream)
{
    const float* Xf   = (const float*)d_in[0];
    const float* Wqkv = (const float*)d_in[1];
    const float* Bqkv = (const float*)d_in[2];
    const float* Wout = (const float*)d_in[3];
    const float* Bout = (const float*)d_in[4];
    const int*   cu   = (const int*)d_in[5];

    const size_t X16_B  = (size_t)4096 * 1152 * 2;
    const size_t WQ16_B = (size_t)3456 * 1152 * 2;
    const size_t WO16_B = (size_t)1152 * 1152 * 2;
    const size_t H_B    = (size_t)16 * 4096 * 72 * 2;

    char* ws = (char*)d_ws;
    bf16* X16  = (bf16*)ws;
    bf16* WQ16 = (bf16*)(ws + X16_B);
    bf16* WO16 = (bf16*)(ws + X16_B + WQ16_B);
    bf16* Qh   = (bf16*)(ws + X16_B + WQ16_B + WO16_B);
    bf16* Kh   = (bf16*)(ws + X16_B + WQ16_B + WO16_B + H_B);
    bf16* Vt   = (bf16*)(ws + X16_B + WQ16_B + WO16_B + 2 * H_B);
    bf16* AO   = (bf16*)(ws + X16_B + WQ16_B + WO16_B + 3 * H_B);
    float* Out = (float*)d_out;

    dim3 blk(256);
    // f32->bf16: 10,027,008 elems / 8 / 256 = 4896 blocks (no zero-fill)
    cvt_all<<<dim3(4896), blk, 0, stream>>>(Xf, X16, 4096 * 1152,
                                            Wqkv, WQ16, 3456 * 1152,
                                            Wout, WO16, 1152 * 1152);

    // QKV projection -> Qh/Kh (row-major repack) + Vt (transpose)
    gemm_qkv<<<dim3(32, 27), blk, 0, stream>>>(X16, WQ16, Bqkv,
                                               Qh, Kh, Vt, 4096, 1152);
    // varlen attention (1-D grid, h = low 4 bits for XCD locality)
    attn_varlen<<<dim3(72 * 16), blk, 0, stream>>>(Qh, Kh, Vt, cu, AO);
    // output projection: 128x64 tiles, 576 blocks, direct f32 stores
    gemm_out<<<dim3(32, 18), blk, 0, stream>>>(AO, WO16, Bout, Out,
                                               4096, 1152, 1152);
}